// Round 2
// baseline (338.039 us; speedup 1.0000x reference)
//
#include <hip/hip_runtime.h>

#define N_NODES 100000
#define N_EDGES 6400000

__global__ void zero_out_kernel(float* __restrict__ out, int n) {
    int i = blockIdx.x * blockDim.x + threadIdx.x;
    if (i < n) out[i] = 0.0f;
}

// edge_index is int32 [2, E] (harness converts integer inputs to int32):
// row 0 = aggregation target (src), row 1 = message source (dst).
// out[src] += w * x[dst]
__global__ void __launch_bounds__(256) scatter_add_kernel(
        const float* __restrict__ x,
        const int* __restrict__ ei,      // [2*E]
        const float* __restrict__ w,     // [E]
        float* __restrict__ out) {
    int t = blockIdx.x * blockDim.x + threadIdx.x;
    int e0 = t * 4;
    if (e0 >= N_EDGES) return;

    const int* srcp = ei;            // row 0
    const int* dstp = ei + N_EDGES;  // row 1

    int4   s4 = *reinterpret_cast<const int4*>(srcp + e0);
    int4   d4 = *reinterpret_cast<const int4*>(dstp + e0);
    float4 w4 = *reinterpret_cast<const float4*>(w + e0);

    float v0 = w4.x * x[d4.x];
    float v1 = w4.y * x[d4.y];
    float v2 = w4.z * x[d4.z];
    float v3 = w4.w * x[d4.w];

    atomicAdd(&out[s4.x], v0);
    atomicAdd(&out[s4.y], v1);
    atomicAdd(&out[s4.z], v2);
    atomicAdd(&out[s4.w], v3);
}

extern "C" void kernel_launch(void* const* d_in, const int* in_sizes, int n_in,
                              void* d_out, int out_size, void* d_ws, size_t ws_size,
                              hipStream_t stream) {
    const float* x   = (const float*)d_in[0];
    const int*   ei  = (const int*)d_in[1];
    const float* w   = (const float*)d_in[2];
    float*       out = (float*)d_out;

    zero_out_kernel<<<(N_NODES + 255) / 256, 256, 0, stream>>>(out, N_NODES);

    int threads = N_EDGES / 4;  // 6.4M divisible by 4
    scatter_add_kernel<<<(threads + 255) / 256, 256, 0, stream>>>(x, ei, w, out);
}

// Round 3
// 323.852 us; speedup vs baseline: 1.0438x; 1.0438x over previous
//
#include <hip/hip_runtime.h>

#define N_NODES 100000
#define N_EDGES 6400000
#define N_XCD 8
#define PARTIAL_FLOATS (N_XCD * N_NODES)

// ---- fallback path (device-scope atomics straight into out) ----
__global__ void zero_out_kernel(float* __restrict__ out, int n) {
    int i = blockIdx.x * blockDim.x + threadIdx.x;
    if (i < n) out[i] = 0.0f;
}

__global__ void __launch_bounds__(256) scatter_direct_kernel(
        const float* __restrict__ x,
        const int* __restrict__ ei,
        const float* __restrict__ w,
        float* __restrict__ out) {
    int t = blockIdx.x * blockDim.x + threadIdx.x;
    int e0 = t * 4;
    if (e0 >= N_EDGES) return;
    int4   s4 = *reinterpret_cast<const int4*>(ei + e0);
    int4   d4 = *reinterpret_cast<const int4*>(ei + N_EDGES + e0);
    float4 w4 = *reinterpret_cast<const float4*>(w + e0);
    atomicAdd(&out[s4.x], w4.x * x[d4.x]);
    atomicAdd(&out[s4.y], w4.y * x[d4.y]);
    atomicAdd(&out[s4.z], w4.z * x[d4.z]);
    atomicAdd(&out[s4.w], w4.w * x[d4.w]);
}

// ---- main path: per-XCD partials with L2-local atomics ----
__global__ void zero_ws_kernel(float4* __restrict__ p, int n4) {
    int i = blockIdx.x * blockDim.x + threadIdx.x;
    if (i < n4) p[i] = make_float4(0.f, 0.f, 0.f, 0.f);
}

__device__ __forceinline__ int xcc_id() {
    int v;
    asm volatile("s_getreg_b32 %0, hwreg(HW_REG_XCC_ID)" : "=s"(v));
    return v & (N_XCD - 1);
}

__global__ void __launch_bounds__(256) scatter_xcd_kernel(
        const float* __restrict__ x,
        const int* __restrict__ ei,
        const float* __restrict__ w,
        float* __restrict__ partial) {
    int t = blockIdx.x * blockDim.x + threadIdx.x;
    int e0 = t * 4;
    if (e0 >= N_EDGES) return;

    float* p = partial + (size_t)xcc_id() * N_NODES;

    int4   s4 = *reinterpret_cast<const int4*>(ei + e0);
    int4   d4 = *reinterpret_cast<const int4*>(ei + N_EDGES + e0);
    float4 w4 = *reinterpret_cast<const float4*>(w + e0);

    // Only waves physically on XCD k touch slice k, so the XCD-local TCC is a
    // legal serialization point -> workgroup scope (no sc1), stays L2-resident.
    __hip_atomic_fetch_add(&p[s4.x], w4.x * x[d4.x], __ATOMIC_RELAXED, __HIP_MEMORY_SCOPE_WORKGROUP);
    __hip_atomic_fetch_add(&p[s4.y], w4.y * x[d4.y], __ATOMIC_RELAXED, __HIP_MEMORY_SCOPE_WORKGROUP);
    __hip_atomic_fetch_add(&p[s4.z], w4.z * x[d4.z], __ATOMIC_RELAXED, __HIP_MEMORY_SCOPE_WORKGROUP);
    __hip_atomic_fetch_add(&p[s4.w], w4.w * x[d4.w], __ATOMIC_RELAXED, __HIP_MEMORY_SCOPE_WORKGROUP);
}

__global__ void reduce_kernel(const float* __restrict__ partial, float* __restrict__ out) {
    int i = blockIdx.x * blockDim.x + threadIdx.x;  // one thread per 4 nodes
    int n0 = i * 4;
    if (n0 >= N_NODES) return;
    float4 acc = *reinterpret_cast<const float4*>(partial + n0);
    #pragma unroll
    for (int k = 1; k < N_XCD; ++k) {
        float4 v = *reinterpret_cast<const float4*>(partial + (size_t)k * N_NODES + n0);
        acc.x += v.x; acc.y += v.y; acc.z += v.z; acc.w += v.w;
    }
    *reinterpret_cast<float4*>(out + n0) = acc;
}

extern "C" void kernel_launch(void* const* d_in, const int* in_sizes, int n_in,
                              void* d_out, int out_size, void* d_ws, size_t ws_size,
                              hipStream_t stream) {
    const float* x   = (const float*)d_in[0];
    const int*   ei  = (const int*)d_in[1];
    const float* w   = (const float*)d_in[2];
    float*       out = (float*)d_out;

    int ethreads = N_EDGES / 4;  // exact

    if (ws_size >= (size_t)PARTIAL_FLOATS * sizeof(float)) {
        float* partial = (float*)d_ws;
        int n4 = PARTIAL_FLOATS / 4;  // 200000
        zero_ws_kernel<<<(n4 + 255) / 256, 256, 0, stream>>>((float4*)partial, n4);
        scatter_xcd_kernel<<<(ethreads + 255) / 256, 256, 0, stream>>>(x, ei, w, partial);
        int rthreads = N_NODES / 4;  // 25000, exact
        reduce_kernel<<<(rthreads + 255) / 256, 256, 0, stream>>>(partial, out);
    } else {
        zero_out_kernel<<<(N_NODES + 255) / 256, 256, 0, stream>>>(out, N_NODES);
        scatter_direct_kernel<<<(ethreads + 255) / 256, 256, 0, stream>>>(x, ei, w, out);
    }
}

// Round 4
// 81.252 us; speedup vs baseline: 4.1604x; 3.9858x over previous
//
#include <hip/hip_runtime.h>

#define N_NODES 100000
#define N_EDGES 6400000
#define RANGES 4
#define RANGE_S 25000   // nodes per range; RANGES * RANGE_S == N_NODES

// ---------- fallback path (device-scope atomics straight into out) ----------
__global__ void zero_out_kernel(float* __restrict__ out, int n) {
    int i = blockIdx.x * blockDim.x + threadIdx.x;
    if (i < n) out[i] = 0.0f;
}

__global__ void __launch_bounds__(256) scatter_direct_kernel(
        const float* __restrict__ x,
        const int* __restrict__ ei,
        const float* __restrict__ w,
        float* __restrict__ out) {
    int t = blockIdx.x * blockDim.x + threadIdx.x;
    int e0 = t * 4;
    if (e0 >= N_EDGES) return;
    int4   s4 = *reinterpret_cast<const int4*>(ei + e0);
    int4   d4 = *reinterpret_cast<const int4*>(ei + N_EDGES + e0);
    float4 w4 = *reinterpret_cast<const float4*>(w + e0);
    atomicAdd(&out[s4.x], w4.x * x[d4.x]);
    atomicAdd(&out[s4.y], w4.y * x[d4.y]);
    atomicAdd(&out[s4.z], w4.z * x[d4.z]);
    atomicAdd(&out[s4.w], w4.w * x[d4.w]);
}

// ---------- main path: node-range partitioning, LDS-private accumulation ----------
// Block (r, c): range r = blockIdx.x & 3, edge-chunk c = blockIdx.x >> 2.
// Consecutive blocks read the SAME chunk for 4 ranges -> L3 temporal locality.
__global__ void __launch_bounds__(1024) scatter_range_kernel(
        const float* __restrict__ x,
        const int* __restrict__ ei,
        const float* __restrict__ w,
        float* __restrict__ partial,
        int nb) {                       // chunks per range
    __shared__ float bins[RANGE_S];     // 100 KB LDS
    const int r = blockIdx.x & (RANGES - 1);
    const int c = blockIdx.x >> 2;

    for (int i = threadIdx.x; i < RANGE_S; i += blockDim.x) bins[i] = 0.0f;
    __syncthreads();

    const int chunk = N_EDGES / nb;     // nb in {8,16,32,64} -> divisible, %4 == 0
    const int base  = c * chunk;
    const int end   = base + chunk;
    const int lo    = r * RANGE_S;
    const int* __restrict__ srcp = ei;
    const int* __restrict__ dstp = ei + N_EDGES;

    for (int e = base + (int)threadIdx.x * 4; e < end; e += (int)blockDim.x * 4) {
        int4   s4 = *reinterpret_cast<const int4*>(srcp + e);
        int4   d4 = *reinterpret_cast<const int4*>(dstp + e);
        float4 w4 = *reinterpret_cast<const float4*>(w + e);
        unsigned a0 = (unsigned)(s4.x - lo), a1 = (unsigned)(s4.y - lo),
                 a2 = (unsigned)(s4.z - lo), a3 = (unsigned)(s4.w - lo);
        if (a0 < RANGE_S) atomicAdd(&bins[a0], w4.x * x[d4.x]);  // ds_add_f32, on-CU
        if (a1 < RANGE_S) atomicAdd(&bins[a1], w4.y * x[d4.y]);
        if (a2 < RANGE_S) atomicAdd(&bins[a2], w4.z * x[d4.z]);
        if (a3 < RANGE_S) atomicAdd(&bins[a3], w4.w * x[d4.w]);
    }
    __syncthreads();

    // full overwrite of this block's partial slice -> no pre-zero of d_ws needed
    float* outp = partial + (size_t)(r * nb + c) * RANGE_S;
    for (int i = threadIdx.x; i < RANGE_S; i += blockDim.x) outp[i] = bins[i];
}

__global__ void reduce_range_kernel(const float* __restrict__ partial,
                                    float* __restrict__ out, int nb) {
    int i = blockIdx.x * blockDim.x + threadIdx.x;  // one thread per 4 nodes
    int n0 = i * 4;
    if (n0 >= N_NODES) return;
    int r = n0 / RANGE_S;
    int s = n0 - r * RANGE_S;                        // RANGE_S % 4 == 0 -> no range straddle
    const float* base = partial + (size_t)(r * nb) * RANGE_S + s;
    float4 acc = make_float4(0.f, 0.f, 0.f, 0.f);
    for (int j = 0; j < nb; ++j) {
        float4 v = *reinterpret_cast<const float4*>(base + (size_t)j * RANGE_S);
        acc.x += v.x; acc.y += v.y; acc.z += v.z; acc.w += v.w;
    }
    *reinterpret_cast<float4*>(out + n0) = acc;
}

extern "C" void kernel_launch(void* const* d_in, const int* in_sizes, int n_in,
                              void* d_out, int out_size, void* d_ws, size_t ws_size,
                              hipStream_t stream) {
    const float* x   = (const float*)d_in[0];
    const int*   ei  = (const int*)d_in[1];
    const float* w   = (const float*)d_in[2];
    float*       out = (float*)d_out;

    // pick largest nb (chunks per range) whose partial buffer fits d_ws
    int nb = 0;
    for (int cand = 64; cand >= 8; cand >>= 1) {
        if (ws_size >= (size_t)RANGES * cand * RANGE_S * sizeof(float)) { nb = cand; break; }
    }

    if (nb > 0) {
        float* partial = (float*)d_ws;
        scatter_range_kernel<<<RANGES * nb, 1024, 0, stream>>>(x, ei, w, partial, nb);
        int rthreads = N_NODES / 4;  // 25000
        reduce_range_kernel<<<(rthreads + 255) / 256, 256, 0, stream>>>(partial, out, nb);
    } else {
        zero_out_kernel<<<(N_NODES + 255) / 256, 256, 0, stream>>>(out, N_NODES);
        int ethreads = N_EDGES / 4;
        scatter_direct_kernel<<<(ethreads + 255) / 256, 256, 0, stream>>>(x, ei, w, out);
    }
}

// Round 5
// 65.378 us; speedup vs baseline: 5.1706x; 1.2428x over previous
//
#include <hip/hip_runtime.h>

#define N_NODES 100000
#define N_EDGES 6400000
#define RANGES 4
#define RANGE_S 25000   // nodes per range; RANGES * RANGE_S == N_NODES
#define NB 64           // chunks per range -> 256 blocks
#define BLK 1024

// ---------- fallback path (device-scope atomics straight into out) ----------
__global__ void zero_out_kernel(float* __restrict__ out, int n) {
    int i = blockIdx.x * blockDim.x + threadIdx.x;
    if (i < n) out[i] = 0.0f;
}

__global__ void __launch_bounds__(256) scatter_direct_kernel(
        const float* __restrict__ x,
        const int* __restrict__ ei,
        const float* __restrict__ w,
        float* __restrict__ out) {
    int t = blockIdx.x * blockDim.x + threadIdx.x;
    int e0 = t * 4;
    if (e0 >= N_EDGES) return;
    int4   s4 = *reinterpret_cast<const int4*>(ei + e0);
    int4   d4 = *reinterpret_cast<const int4*>(ei + N_EDGES + e0);
    float4 w4 = *reinterpret_cast<const float4*>(w + e0);
    atomicAdd(&out[s4.x], w4.x * x[d4.x]);
    atomicAdd(&out[s4.y], w4.y * x[d4.y]);
    atomicAdd(&out[s4.z], w4.z * x[d4.z]);
    atomicAdd(&out[s4.w], w4.w * x[d4.w]);
}

// ---------- main path: range partitioning, LDS bins, branchless gathers ----------
__global__ void __launch_bounds__(BLK) scatter_range_kernel(
        const float* __restrict__ x,
        const int* __restrict__ ei,
        const float* __restrict__ w,
        float* __restrict__ partial) {
    __shared__ float bins[RANGE_S];     // 100 KB LDS
    const int r = blockIdx.x & (RANGES - 1);
    const int c = blockIdx.x >> 2;

    for (int i = threadIdx.x; i < RANGE_S; i += BLK) bins[i] = 0.0f;
    __syncthreads();

    const int chunk = N_EDGES / NB;     // 100000
    const int base  = c * chunk;
    const int end   = base + chunk;
    const int lo    = r * RANGE_S;
    const int* __restrict__ srcp = ei;
    const int* __restrict__ dstp = ei + N_EDGES;

    // 8 edges per thread per iteration; all loads issued before any use.
    for (int e = base + (int)threadIdx.x * 8; e < end; e += BLK * 8) {
        int4   sa = *reinterpret_cast<const int4*>(srcp + e);
        int4   sb = *reinterpret_cast<const int4*>(srcp + e + 4);
        int4   da = *reinterpret_cast<const int4*>(dstp + e);
        int4   db = *reinterpret_cast<const int4*>(dstp + e + 4);
        float4 wa = *reinterpret_cast<const float4*>(w + e);
        float4 wb = *reinterpret_cast<const float4*>(w + e + 4);

        unsigned a[8] = {
            (unsigned)(sa.x - lo), (unsigned)(sa.y - lo),
            (unsigned)(sa.z - lo), (unsigned)(sa.w - lo),
            (unsigned)(sb.x - lo), (unsigned)(sb.y - lo),
            (unsigned)(sb.z - lo), (unsigned)(sb.w - lo)
        };
        int d[8] = { da.x, da.y, da.z, da.w, db.x, db.y, db.z, db.w };
        float ww[8] = { wa.x, wa.y, wa.z, wa.w, wb.x, wb.y, wb.z, wb.w };

        // Branchless gathers: non-owning lanes broadcast-read x[0] (one line).
        float xv[8];
        #pragma unroll
        for (int k = 0; k < 8; ++k) {
            int gi = (a[k] < RANGE_S) ? d[k] : 0;
            xv[k] = x[gi];
        }
        // Pin the gathers so the compiler can't sink them into the branches.
        #pragma unroll
        for (int k = 0; k < 8; ++k) asm volatile("" : "+v"(xv[k]));

        // Only the short-latency LDS atomic stays predicated.
        #pragma unroll
        for (int k = 0; k < 8; ++k) {
            if (a[k] < RANGE_S) atomicAdd(&bins[a[k]], ww[k] * xv[k]);
        }
    }
    __syncthreads();

    float* outp = partial + (size_t)(r * NB + c) * RANGE_S;
    for (int i = threadIdx.x; i < RANGE_S; i += BLK) outp[i] = bins[i];
}

__global__ void reduce_range_kernel(const float* __restrict__ partial,
                                    float* __restrict__ out) {
    int i = blockIdx.x * blockDim.x + threadIdx.x;  // one thread per 4 nodes
    int n0 = i * 4;
    if (n0 >= N_NODES) return;
    int r = n0 / RANGE_S;
    int s = n0 - r * RANGE_S;                        // RANGE_S % 4 == 0
    const float* base = partial + (size_t)(r * NB) * RANGE_S + s;
    float4 acc = make_float4(0.f, 0.f, 0.f, 0.f);
    for (int j = 0; j < NB; ++j) {
        float4 v = *reinterpret_cast<const float4*>(base + (size_t)j * RANGE_S);
        acc.x += v.x; acc.y += v.y; acc.z += v.z; acc.w += v.w;
    }
    *reinterpret_cast<float4*>(out + n0) = acc;
}

extern "C" void kernel_launch(void* const* d_in, const int* in_sizes, int n_in,
                              void* d_out, int out_size, void* d_ws, size_t ws_size,
                              hipStream_t stream) {
    const float* x   = (const float*)d_in[0];
    const int*   ei  = (const int*)d_in[1];
    const float* w   = (const float*)d_in[2];
    float*       out = (float*)d_out;

    if (ws_size >= (size_t)RANGES * NB * RANGE_S * sizeof(float)) {
        float* partial = (float*)d_ws;
        scatter_range_kernel<<<RANGES * NB, BLK, 0, stream>>>(x, ei, w, partial);
        int rthreads = N_NODES / 4;  // 25000
        reduce_range_kernel<<<(rthreads + 255) / 256, 256, 0, stream>>>(partial, out);
    } else {
        zero_out_kernel<<<(N_NODES + 255) / 256, 256, 0, stream>>>(out, N_NODES);
        int ethreads = N_EDGES / 4;
        scatter_direct_kernel<<<(ethreads + 255) / 256, 256, 0, stream>>>(x, ei, w, out);
    }
}